// Round 2
// baseline (8165.441 us; speedup 1.0000x reference)
//
#include <hip/hip_runtime.h>

#define B_ 256
#define T_ 128
#define E_ 512
#define H_ 512
#define NG 2048   // 4*H_
#define NB 256    // persistent blocks (== CU count)
#define NT 512    // threads per block (8 waves)

typedef __attribute__((ext_vector_type(8))) short bf16x8;
typedef __attribute__((ext_vector_type(4))) float f32x4;

__device__ __forceinline__ short f2bf(float f) {
  union { float f; unsigned u; } x; x.f = f;
  unsigned r = x.u + 0x7FFFu + ((x.u >> 16) & 1u);  // RNE
  return (short)(r >> 16);
}
__device__ __forceinline__ float bf2f(short s) {
  union { unsigned u; float f; } x;
  x.u = ((unsigned)(unsigned short)s) << 16; return x.f;
}
__device__ __forceinline__ float sigm(float x) { return 1.0f / (1.0f + __expf(-x)); }

// ---- Wt[j][k] = bf16( k<512 ? Wx[k][j] : Uh[k-512][j] ), j in [0,2048), k in [0,1024)
__global__ __launch_bounds__(256) void prep_w(const float* __restrict__ Wx,
                                              const float* __restrict__ Uh,
                                              short* __restrict__ Wt) {
  __shared__ float tile[64][65];
  const int k0 = blockIdx.x * 64;   // 16 blocks
  const int j0 = blockIdx.y * 64;   // 32 blocks
  const int tx = threadIdx.x & 63, ty = threadIdx.x >> 6;  // ty 0..3
#pragma unroll
  for (int r = 0; r < 16; ++r) {
    int k = k0 + r * 4 + ty;
    float v = (k < 512) ? Wx[(size_t)k * NG + j0 + tx]
                        : Uh[(size_t)(k - 512) * NG + j0 + tx];
    tile[r * 4 + ty][tx] = v;
  }
  __syncthreads();
#pragma unroll
  for (int r = 0; r < 16; ++r) {
    int j = j0 + r * 4 + ty;
    Wt[(size_t)j * 1024 + k0 + tx] = f2bf(tile[tx][r * 4 + ty]);
  }
}

// ---- xs[t][b][e] = bf16(emb[captions[b][t]][e]), zero row for token 0 (padding_idx)
__global__ __launch_bounds__(256) void stage_x(const int* __restrict__ captions,
                                               const float* __restrict__ emb,
                                               short* __restrict__ xs) {
  const int bid = blockIdx.x;          // = t*B_ + b
  const int t = bid >> 8, b = bid & 255;
  const int tok = captions[b * T_ + t];
  short* o = xs + (size_t)bid * E_;
  const float* src = emb + (size_t)tok * E_;
  int e0 = threadIdx.x, e1 = threadIdx.x + 256;
  if (tok) { o[e0] = f2bf(src[e0]); o[e1] = f2bf(src[e1]); }
  else     { o[e0] = 0;             o[e1] = 0; }
}

// ---- device-scope sense-reversing grid barrier
__device__ __forceinline__ void grid_bar(unsigned* cnt, unsigned* gen) {
  __threadfence();
  __syncthreads();
  if (threadIdx.x == 0) {
    unsigned g = __hip_atomic_load(gen, __ATOMIC_RELAXED, __HIP_MEMORY_SCOPE_AGENT);
    unsigned a = __hip_atomic_fetch_add(cnt, 1u, __ATOMIC_ACQ_REL, __HIP_MEMORY_SCOPE_AGENT);
    if (a == NB - 1) {
      __hip_atomic_store(cnt, 0u, __ATOMIC_RELAXED, __HIP_MEMORY_SCOPE_AGENT);
      __hip_atomic_store(gen, g + 1u, __ATOMIC_RELEASE, __HIP_MEMORY_SCOPE_AGENT);
    } else {
      while (__hip_atomic_load(gen, __ATOMIC_ACQUIRE, __HIP_MEMORY_SCOPE_AGENT) == g) {}
    }
  }
  __syncthreads();
}

// ---- persistent kernel: all 128 LSTM steps.
// grid 256 = 8 m-groups (32 rows) x 32 j-tiles (16 hidden cols).
// 8 waves = (m-half mh in {0,1}) x (K-quarter kq in {0..3}); each wave computes
// 4 gate-tiles (16x16) over its 256-wide K slice; partials reduced through LDS.
// Weights (64 cols x 1024 K, bf16, XOR-swizzled) live in LDS for all 128 steps.
// Cell state c lives in registers. h is triple-buffered in global bf16.
__global__ __launch_bounds__(NT, 1) void lstm_all(
    const short* __restrict__ xs,   // [T][B][E] bf16
    const short* __restrict__ Wt,   // [2048][1024] bf16
    const float* __restrict__ bx, const float* __restrict__ bu,
    short* __restrict__ h0, short* __restrict__ h1, short* __restrict__ h2,
    unsigned* __restrict__ bar) {
  __shared__ short wlds[4 * 16 * 1024];          // 128 KB
  __shared__ float red[2][2][4][16][16];         // 16 KB  (mh, slot, gate, row, col)
  __shared__ float gbuf[2][4][16][16];           // 8 KB

  const int tid = threadIdx.x;
  const int wid = tid >> 6, lane = tid & 63;
  const int l15 = lane & 15, l4 = lane >> 4;
  const int mh = wid & 1, kq = wid >> 1;
  const int mg = blockIdx.x >> 5, jt = blockIdx.x & 31;
  const int j0 = jt * 16;
  const int rA = mg * 32 + mh * 16 + l15;

  // ---- stage weights into LDS (swizzled: short-offset ^= (col&7)<<3)
  for (int r8 = 0; r8 < 8; ++r8) {
    const int row = wid * 8 + r8;              // 0..63
    const int g = row >> 4, col = row & 15;
    const short* src = Wt + (size_t)(g * 512 + j0 + col) * 1024;
#pragma unroll
    for (int rep = 0; rep < 2; ++rep) {
      int soff = lane * 8 + rep * 512;
      *(bf16x8*)&wlds[row * 1024 + (soff ^ ((col & 7) << 3))] =
          *(const bf16x8*)(src + soff);
    }
  }

  // ---- per-thread gate-math constants & cell state
  const int mh2 = tid >> 8, rr = (tid >> 4) & 15, jj = tid & 15;
  const int J = j0 + jj;
  const float bi = bx[J] + bu[J];
  const float bf_ = bx[512 + J] + bu[512 + J];
  const float bo = bx[1024 + J] + bu[1024 + J];
  const float bg = bx[1536 + J] + bu[1536 + J];
  const int hidx = (mg * 32 + mh2 * 16 + rr) * 512 + J;
  float c_reg = 0.f;

  __syncthreads();

  short* hb[3] = {h0, h1, h2};
  for (int t = 0; t < T_; ++t) {
    const short* hin = hb[t % 3];
    short* hout = hb[(t + 1) % 3];

    f32x4 acc[4] = {{0,0,0,0},{0,0,0,0},{0,0,0,0},{0,0,0,0}};
    const short* abase = (kq < 2)
        ? xs + (size_t)(t * B_ + rA) * E_ + kq * 256 + l4 * 8
        : hin + (size_t)rA * H_ + (kq - 2) * 256 + l4 * 8;
#pragma unroll
    for (int ks = 0; ks < 8; ++ks) {
      bf16x8 a = *(const bf16x8*)(abase + ks * 32);
      const int swz = (kq * 256 + ks * 32 + l4 * 8) ^ ((l15 & 7) << 3);
#pragma unroll
      for (int g = 0; g < 4; ++g) {
        bf16x8 bw = *(const bf16x8*)&wlds[(g * 16 + l15) * 1024 + swz];
        acc[g] = __builtin_amdgcn_mfma_f32_16x16x32_bf16(a, bw, acc[g], 0, 0, 0);
      }
    }

    // ---- K-quarter reduction: kq1->slot0, kq3->slot1; kq0+=s0; kq2+=s1->s1; kq0 final
    if (kq & 1) {
      const int slot = kq >> 1;
#pragma unroll
      for (int g = 0; g < 4; ++g)
#pragma unroll
        for (int r = 0; r < 4; ++r)
          red[mh][slot][g][l4 * 4 + r][l15] = acc[g][r];
    }
    __syncthreads();
    if (kq == 0) {
#pragma unroll
      for (int g = 0; g < 4; ++g)
#pragma unroll
        for (int r = 0; r < 4; ++r)
          acc[g][r] += red[mh][0][g][l4 * 4 + r][l15];
    } else if (kq == 2) {
#pragma unroll
      for (int g = 0; g < 4; ++g)
#pragma unroll
        for (int r = 0; r < 4; ++r)
          red[mh][1][g][l4 * 4 + r][l15] += acc[g][r];  // own slot: read-modify-write
    }
    __syncthreads();
    if (kq == 0) {
#pragma unroll
      for (int g = 0; g < 4; ++g)
#pragma unroll
        for (int r = 0; r < 4; ++r)
          gbuf[mh][g][l4 * 4 + r][l15] = acc[g][r] + red[mh][1][g][l4 * 4 + r][l15];
    }
    __syncthreads();

    // ---- gate math; c in registers; h -> global bf16
    {
      float iv = gbuf[mh2][0][rr][jj] + bi;
      float fv = gbuf[mh2][1][rr][jj] + bf_;
      float ov = gbuf[mh2][2][rr][jj] + bo;
      float gv = gbuf[mh2][3][rr][jj] + bg;
      float cn = sigm(fv) * c_reg + sigm(iv) * tanhf(gv);
      c_reg = cn;
      hout[hidx] = f2bf(sigm(ov) * tanhf(cn));
    }
    grid_bar(bar, bar + 1);
  }
}

// ---- out[b,:] = normalize( h_last[b,:] @ fcW + fcb ); one block per batch row
__global__ __launch_bounds__(256) void final_fc(const short* __restrict__ h,
                                                const float* __restrict__ fcW,
                                                const float* __restrict__ fcb,
                                                float* __restrict__ out) {
  const int b = blockIdx.x, tid = threadIdx.x;
  __shared__ float hrow[512];
  __shared__ float red[256];
  for (int k = tid; k < 512; k += 256) hrow[k] = bf2f(h[b * 512 + k]);
  __syncthreads();
  float a0 = fcb[tid], a1 = fcb[tid + 256];
  for (int k = 0; k < 512; ++k) {
    float hv = hrow[k];
    a0 += hv * fcW[(size_t)k * 512 + tid];
    a1 += hv * fcW[(size_t)k * 512 + tid + 256];
  }
  red[tid] = a0 * a0 + a1 * a1;
  __syncthreads();
  for (int s = 128; s > 0; s >>= 1) {
    if (tid < s) red[tid] += red[tid + s];
    __syncthreads();
  }
  float scale = 1.0f / fmaxf(sqrtf(red[0]), 1e-12f);
  out[(size_t)b * 512 + tid] = a0 * scale;
  out[(size_t)b * 512 + tid + 256] = a1 * scale;
}

extern "C" void kernel_launch(void* const* d_in, const int* in_sizes, int n_in,
                              void* d_out, int out_size, void* d_ws, size_t ws_size,
                              hipStream_t stream) {
  const int*   captions = (const int*)d_in[0];
  const float* emb      = (const float*)d_in[1];
  const float* Wx       = (const float*)d_in[2];
  const float* bx       = (const float*)d_in[3];
  const float* Uh       = (const float*)d_in[4];
  const float* bu       = (const float*)d_in[5];
  const float* fcW      = (const float*)d_in[6];
  const float* fcb      = (const float*)d_in[7];
  float* out = (float*)d_out;

  char* ws = (char*)d_ws;
  size_t off = 0;
  auto alloc = [&](size_t bytes) {
    char* p = ws + off;
    off += (bytes + 255) & ~(size_t)255;
    return p;
  };
  short* Wt = (short*)alloc((size_t)NG * 1024 * 2);       // 4 MB
  short* xs = (short*)alloc((size_t)T_ * B_ * E_ * 2);    // 32 MB
  short* h0 = (short*)alloc((size_t)B_ * H_ * 2);
  short* h1 = (short*)alloc((size_t)B_ * H_ * 2);
  short* h2 = (short*)alloc((size_t)B_ * H_ * 2);
  unsigned* bar = (unsigned*)alloc(256);

  hipMemsetAsync(h0, 0, (size_t)B_ * H_ * 2, stream);
  hipMemsetAsync(bar, 0, 256, stream);

  prep_w<<<dim3(16, 32), 256, 0, stream>>>(Wx, Uh, Wt);
  stage_x<<<T_ * B_, 256, 0, stream>>>(captions, emb, xs);

  void* kargs[] = {(void*)&xs, (void*)&Wt, (void*)&bx, (void*)&bu,
                   (void*)&h0, (void*)&h1, (void*)&h2, (void*)&bar};
  hipLaunchCooperativeKernel((const void*)lstm_all, dim3(NB), dim3(NT),
                             kargs, 0, stream);

  // t=127 wrote hb[(127+1)%3] = h2
  final_fc<<<B_, 256, 0, stream>>>(h2, fcW, fcb, out);
}

// Round 3
// 802.900 us; speedup vs baseline: 10.1699x; 10.1699x over previous
//
#include <hip/hip_runtime.h>

#define B_ 256
#define T_ 128
#define E_ 512
#define H_ 512
#define NG 2048   // 4*H_
#define NB 256    // persistent blocks
#define NT 512    // threads per block (8 waves)

typedef __attribute__((ext_vector_type(8))) short bf16x8;
typedef __attribute__((ext_vector_type(4))) float f32x4;

__device__ __forceinline__ short f2bf(float f) {
  union { float f; unsigned u; } x; x.f = f;
  unsigned r = x.u + 0x7FFFu + ((x.u >> 16) & 1u);  // RNE
  return (short)(r >> 16);
}
__device__ __forceinline__ float bf2f(short s) {
  union { unsigned u; float f; } x;
  x.u = ((unsigned)(unsigned short)s) << 16; return x.f;
}
__device__ __forceinline__ float sigm(float x) { return 1.0f / (1.0f + __expf(-x)); }

// ---- Wt[j][k] = bf16( k<512 ? Wx[k][j] : Uh[k-512][j] )
__global__ __launch_bounds__(256) void prep_w(const float* __restrict__ Wx,
                                              const float* __restrict__ Uh,
                                              short* __restrict__ Wt) {
  __shared__ float tile[64][65];
  const int k0 = blockIdx.x * 64;   // 16 blocks
  const int j0 = blockIdx.y * 64;   // 32 blocks
  const int tx = threadIdx.x & 63, ty = threadIdx.x >> 6;
#pragma unroll
  for (int r = 0; r < 16; ++r) {
    int k = k0 + r * 4 + ty;
    float v = (k < 512) ? Wx[(size_t)k * NG + j0 + tx]
                        : Uh[(size_t)(k - 512) * NG + j0 + tx];
    tile[r * 4 + ty][tx] = v;
  }
  __syncthreads();
#pragma unroll
  for (int r = 0; r < 16; ++r) {
    int j = j0 + r * 4 + ty;
    Wt[(size_t)j * 1024 + k0 + tx] = f2bf(tile[tx][r * 4 + ty]);
  }
}

// ---- xs[t][b][e] = bf16(emb[captions[b][t]][e]); padding_idx=0 row zeroed
__global__ __launch_bounds__(256) void stage_x(const int* __restrict__ captions,
                                               const float* __restrict__ emb,
                                               short* __restrict__ xs) {
  const int bid = blockIdx.x;          // = t*B_ + b
  const int t = bid >> 8, b = bid & 255;
  const int tok = captions[b * T_ + t];
  short* o = xs + (size_t)bid * E_;
  const float* src = emb + (size_t)tok * E_;
  int e0 = threadIdx.x, e1 = threadIdx.x + 256;
  if (tok) { o[e0] = f2bf(src[e0]); o[e1] = f2bf(src[e1]); }
  else     { o[e0] = 0;             o[e1] = 0; }
}

// ---- persistent kernel: all 128 LSTM steps.
// grid 256 = 8 m-groups (mg = bid&7, 32 batch rows) x 32 j-tiles (16 hidden cols).
// Groups are fully independent (batch rows don't interact) -> sync is per-group
// flag array, relaxed agent atomics only (no fences, no RMW, no in-loop acquire).
// h exchanged as packed 2xbf16 uints via device-coherent relaxed atomics.
__global__ __launch_bounds__(NT, 1) void lstm_all(
    const short* __restrict__ xs,   // [T][B][E] bf16
    const short* __restrict__ Wt,   // [2048][1024] bf16
    const float* __restrict__ bx, const float* __restrict__ bu,
    unsigned* __restrict__ h0, unsigned* __restrict__ h1, unsigned* __restrict__ h2,
    unsigned* __restrict__ flags) { // [8 groups][32 blocks] stride 32 uints
  __shared__ short wlds[4 * 16 * 1024];          // 128 KB
  __shared__ float red[2][2][4][16][16];         // 16 KB
  __shared__ float gbuf[2][4][16][16];           // 8 KB

  const int tid = threadIdx.x;
  const int wid = tid >> 6, lane = tid & 63;
  const int l15 = lane & 15, l4 = lane >> 4;
  const int mh = wid & 1, kq = wid >> 1;
  const int mg = blockIdx.x & 7, jt = blockIdx.x >> 3;
  const int j0 = jt * 16;
  const int rA = mg * 32 + mh * 16 + l15;

  // ---- stage weights into LDS (swizzled: short-offset ^= (col&7)<<3)
  for (int r8 = 0; r8 < 8; ++r8) {
    const int row = wid * 8 + r8;              // 0..63
    const int g = row >> 4, col = row & 15;
    const short* src = Wt + (size_t)(g * 512 + j0 + col) * 1024;
#pragma unroll
    for (int rep = 0; rep < 2; ++rep) {
      int soff = lane * 8 + rep * 512;
      *(bf16x8*)&wlds[row * 1024 + (soff ^ ((col & 7) << 3))] =
          *(const bf16x8*)(src + soff);
    }
  }

  // ---- per-thread gate-math constants & cell state
  const int mh2 = tid >> 8, rr = (tid >> 4) & 15, jj = tid & 15;
  const int J = j0 + jj;
  const float bi  = bx[J] + bu[J];
  const float bf_ = bx[512 + J] + bu[512 + J];
  const float bo  = bx[1024 + J] + bu[1024 + J];
  const float bg  = bx[1536 + J] + bu[1536 + J];
  const int Rrow = mg * 32 + mh2 * 16 + rr;
  const int hpk = Rrow * 256 + ((j0 + jj) >> 1);   // packed-uint index (even jj stores)
  float c_reg = 0.f;

  unsigned* hb[3] = {h0, h1, h2};
  unsigned* fl = flags + mg * 32 * 32;

  __syncthreads();

  for (int t = 0; t < T_; ++t) {
    const unsigned* hin = hb[t % 3];
    unsigned* hout = hb[(t + 1) % 3];

    // ---- A-fragment preload (hoisted so loads pipeline)
    bf16x8 af[8];
    if (kq < 2) {
      const short* ab = xs + ((size_t)t * B_ + rA) * E_ + kq * 256 + l4 * 8;
#pragma unroll
      for (int ks = 0; ks < 8; ++ks) af[ks] = *(const bf16x8*)(ab + ks * 32);
    } else {
      // wait for this group's h_t tiles (flags >= t); relaxed polls, no fence
      if (lane < 32) {
        while (__hip_atomic_load(&fl[lane * 32], __ATOMIC_RELAXED,
                                 __HIP_MEMORY_SCOPE_AGENT) < (unsigned)t)
          __builtin_amdgcn_s_sleep(1);
      }
      asm volatile("" ::: "memory");
      const unsigned long long* ab = (const unsigned long long*)
          (hin + (size_t)rA * 256 + (kq - 2) * 128 + l4 * 4);
#pragma unroll
      for (int ks = 0; ks < 8; ++ks) {
        union { bf16x8 v; unsigned long long u[2]; } tmp;
        tmp.u[0] = __hip_atomic_load(ab + ks * 8,     __ATOMIC_RELAXED, __HIP_MEMORY_SCOPE_AGENT);
        tmp.u[1] = __hip_atomic_load(ab + ks * 8 + 1, __ATOMIC_RELAXED, __HIP_MEMORY_SCOPE_AGENT);
        af[ks] = tmp.v;
      }
    }

    // ---- MFMA over this wave's 256-wide K slice, 4 gate tiles
    f32x4 acc[4] = {{0,0,0,0},{0,0,0,0},{0,0,0,0},{0,0,0,0}};
#pragma unroll
    for (int ks = 0; ks < 8; ++ks) {
      const int swz = (kq * 256 + ks * 32 + l4 * 8) ^ ((l15 & 7) << 3);
#pragma unroll
      for (int g = 0; g < 4; ++g) {
        bf16x8 bw = *(const bf16x8*)&wlds[(g * 16 + l15) * 1024 + swz];
        acc[g] = __builtin_amdgcn_mfma_f32_16x16x32_bf16(af[ks], bw, acc[g], 0, 0, 0);
      }
    }

    // ---- K-quarter reduction through LDS
    if (kq & 1) {
      const int slot = kq >> 1;
#pragma unroll
      for (int g = 0; g < 4; ++g)
#pragma unroll
        for (int r = 0; r < 4; ++r)
          red[mh][slot][g][l4 * 4 + r][l15] = acc[g][r];
    }
    __syncthreads();                                   // SYNC1
    if (kq == 0) {
#pragma unroll
      for (int g = 0; g < 4; ++g)
#pragma unroll
        for (int r = 0; r < 4; ++r)
          acc[g][r] += red[mh][0][g][l4 * 4 + r][l15];
    } else if (kq == 2) {
#pragma unroll
      for (int g = 0; g < 4; ++g)
#pragma unroll
        for (int r = 0; r < 4; ++r)
          red[mh][1][g][l4 * 4 + r][l15] += acc[g][r];
    }
    __syncthreads();                                   // SYNC2
    if (kq == 0) {
#pragma unroll
      for (int g = 0; g < 4; ++g)
#pragma unroll
        for (int r = 0; r < 4; ++r)
          gbuf[mh][g][l4 * 4 + r][l15] = acc[g][r] + red[mh][1][g][l4 * 4 + r][l15];
    }
    __syncthreads();                                   // SYNC3

    // ---- gate math; c in registers; h -> packed uint via relaxed agent store
    {
      float iv = gbuf[mh2][0][rr][jj] + bi;
      float fv = gbuf[mh2][1][rr][jj] + bf_;
      float ov = gbuf[mh2][2][rr][jj] + bo;
      float gv = gbuf[mh2][3][rr][jj] + bg;
      float cn = sigm(fv) * c_reg + sigm(iv) * tanhf(gv);
      c_reg = cn;
      unsigned mine = (unsigned)(unsigned short)f2bf(sigm(ov) * tanhf(cn));
      unsigned other = (unsigned)__shfl_xor((int)mine, 1, 64);
      if (!(jj & 1))
        __hip_atomic_store(&hout[hpk], mine | (other << 16),
                           __ATOMIC_RELAXED, __HIP_MEMORY_SCOPE_AGENT);
    }

    // ---- signal: all h stores done (per-wave vmcnt, then block barrier), flag := t+1
    asm volatile("s_waitcnt vmcnt(0)" ::: "memory");
    __syncthreads();                                   // SYNC4
    if (t < T_ - 1 && tid == 0)
      __hip_atomic_store(&fl[jt * 32], (unsigned)(t + 1),
                         __ATOMIC_RELAXED, __HIP_MEMORY_SCOPE_AGENT);
  }
}

// ---- out[b,:] = normalize( h_last[b,:] @ fcW + fcb )
__global__ __launch_bounds__(256) void final_fc(const short* __restrict__ h,
                                                const float* __restrict__ fcW,
                                                const float* __restrict__ fcb,
                                                float* __restrict__ out) {
  const int b = blockIdx.x, tid = threadIdx.x;
  __shared__ float hrow[512];
  __shared__ float red[256];
  for (int k = tid; k < 512; k += 256) hrow[k] = bf2f(h[b * 512 + k]);
  __syncthreads();
  float a0 = fcb[tid], a1 = fcb[tid + 256];
  for (int k = 0; k < 512; ++k) {
    float hv = hrow[k];
    a0 += hv * fcW[(size_t)k * 512 + tid];
    a1 += hv * fcW[(size_t)k * 512 + tid + 256];
  }
  red[tid] = a0 * a0 + a1 * a1;
  __syncthreads();
  for (int s = 128; s > 0; s >>= 1) {
    if (tid < s) red[tid] += red[tid + s];
    __syncthreads();
  }
  float scale = 1.0f / fmaxf(sqrtf(red[0]), 1e-12f);
  out[(size_t)b * 512 + tid] = a0 * scale;
  out[(size_t)b * 512 + tid + 256] = a1 * scale;
}

extern "C" void kernel_launch(void* const* d_in, const int* in_sizes, int n_in,
                              void* d_out, int out_size, void* d_ws, size_t ws_size,
                              hipStream_t stream) {
  const int*   captions = (const int*)d_in[0];
  const float* emb      = (const float*)d_in[1];
  const float* Wx       = (const float*)d_in[2];
  const float* bx       = (const float*)d_in[3];
  const float* Uh       = (const float*)d_in[4];
  const float* bu       = (const float*)d_in[5];
  const float* fcW      = (const float*)d_in[6];
  const float* fcb      = (const float*)d_in[7];
  float* out = (float*)d_out;

  char* ws = (char*)d_ws;
  size_t off = 0;
  auto alloc = [&](size_t bytes) {
    char* p = ws + off;
    off += (bytes + 255) & ~(size_t)255;
    return p;
  };
  short*    Wt    = (short*)alloc((size_t)NG * 1024 * 2);     // 4 MB
  short*    xs    = (short*)alloc((size_t)T_ * B_ * E_ * 2);  // 32 MB
  unsigned* h0    = (unsigned*)alloc((size_t)B_ * H_ * 2);    // 256 KB
  unsigned* h1    = (unsigned*)alloc((size_t)B_ * H_ * 2);
  unsigned* h2    = (unsigned*)alloc((size_t)B_ * H_ * 2);
  unsigned* flags = (unsigned*)alloc(8 * 32 * 32 * 4);        // 32 KB

  hipMemsetAsync(h0, 0, (size_t)B_ * H_ * 2, stream);
  hipMemsetAsync(flags, 0, 8 * 32 * 32 * 4, stream);

  prep_w<<<dim3(16, 32), 256, 0, stream>>>(Wx, Uh, Wt);
  stage_x<<<T_ * B_, 256, 0, stream>>>(captions, emb, xs);

  void* kargs[] = {(void*)&xs, (void*)&Wt, (void*)&bx, (void*)&bu,
                   (void*)&h0, (void*)&h1, (void*)&h2, (void*)&flags};
  hipLaunchCooperativeKernel((const void*)lstm_all, dim3(NB), dim3(NT),
                             kargs, 0, stream);

  // t=127 wrote hb[(127+1)%3] = h2
  final_fc<<<B_, 256, 0, stream>>>((const short*)h2, fcW, fcb, out);
}